// Round 15
// baseline (21.309 us; speedup 1.0000x reference)
//
#include <hip/hip_runtime.h>
#include <math.h>

// PIT SI-SDR loss, B=32, C=3, T=96000, fp32 in, scalar fp32 out.
// R15 = R14 (nt loads) with 2 blocks/CU (tail-overlap A/B under nt):
//  (1) pit_partial: 512 blocks (2/CU) x 512 threads, 1500 float4 per block,
//      ALL 18 nt loads issued up front (whole chunk in flight, ~105 VGPR
//      under the (512,2) cap of 128).
//  (2) pit_finish: one block, 16-chunk column sums + 3x3 pair matrix +
//      6-perm max + -mean.
// All reductions fixed-tree -> deterministic.

#define T_LEN  96000
#define T4     24000           // T in float4
#define B_SZ   32
#define NACC   21              // 3 se + 3 se2 + 3 sr + 3 sr2 + 9 dot
#define NPAIR  (B_SZ * NACC)   // 672
#define NCHUNK 16              // chunks per batch; 16*1500 = 24000 exactly
#define CHUNK4 1500            // float4 per chunk (no ragged remainder)
#define NBLK   (B_SZ * NCHUNK) // 512 blocks = 2 blocks/CU on 256 CUs
#define EPSF   1e-8f

typedef float f32x4 __attribute__((ext_vector_type(4)));

__global__ __launch_bounds__(512, 2) void pit_partial(const float* __restrict__ est,
                                                      const float* __restrict__ ref,
                                                      float* __restrict__ part) {
    const int b     = blockIdx.x >> 4;   // / NCHUNK
    const int chunk = blockIdx.x & 15;   // % NCHUNK

    const f32x4* e4 = reinterpret_cast<const f32x4*>(est) + (size_t)b * 3 * T4;
    const f32x4* r4 = reinterpret_cast<const f32x4*>(ref) + (size_t)b * 3 * T4;

    float se0=0.f, se1=0.f, se2=0.f;          // sum est
    float q0 =0.f, q1 =0.f, q2 =0.f;          // sum est^2
    float sr0=0.f, sr1=0.f, sr2=0.f;          // sum ref
    float w0 =0.f, w1 =0.f, w2 =0.f;          // sum ref^2
    float d00=0.f,d01=0.f,d02=0.f;            // dots est_i . ref_j
    float d10=0.f,d11=0.f,d12=0.f;
    float d20=0.f,d21=0.f,d22=0.f;

#define ACC(E0,E1,E2,R0,R1,R2) do {                                   \
        se0 += (E0); se1 += (E1); se2 += (E2);                        \
        q0  += (E0)*(E0); q1 += (E1)*(E1); q2 += (E2)*(E2);           \
        sr0 += (R0); sr1 += (R1); sr2 += (R2);                        \
        w0  += (R0)*(R0); w1 += (R1)*(R1); w2 += (R2)*(R2);           \
        d00 += (E0)*(R0); d01 += (E0)*(R1); d02 += (E0)*(R2);         \
        d10 += (E1)*(R0); d11 += (E1)*(R1); d12 += (E1)*(R2);         \
        d20 += (E2)*(R0); d21 += (E2)*(R1); d22 += (E2)*(R2);         \
    } while (0)

#define ACCG(A0,A1,A2,C0,C1,C2) do {                                  \
        ACC((A0).x, (A1).x, (A2).x, (C0).x, (C1).x, (C2).x);          \
        ACC((A0).y, (A1).y, (A2).y, (C0).y, (C1).y, (C2).y);          \
        ACC((A0).z, (A1).z, (A2).z, (C0).z, (C1).z, (C2).z);          \
        ACC((A0).w, (A1).w, (A2).w, (C0).w, (C1).w, (C2).w);          \
    } while (0)

#define NTL(P) __builtin_nontemporal_load(P)

#define LOADG(G, T) \
        const f32x4 a##G##0 = NTL(&e4[(T)]);            \
        const f32x4 a##G##1 = NTL(&e4[T4 + (T)]);       \
        const f32x4 a##G##2 = NTL(&e4[2 * T4 + (T)]);   \
        const f32x4 c##G##0 = NTL(&r4[(T)]);            \
        const f32x4 c##G##1 = NTL(&r4[T4 + (T)]);       \
        const f32x4 c##G##2 = NTL(&r4[2 * T4 + (T)])

    // 1500 float4 per chunk: 2 full groups of 512 + tail group of 476.
    const int tid = (int)threadIdx.x;
    const int t0  = chunk * CHUNK4 + tid;
    const int t1  = t0 + 512;
    const bool g2 = (tid < (CHUNK4 - 1024));   // tid < 476
    const int t2  = g2 ? (t0 + 1024) : t0;     // always in-bounds

    // ---- issue ALL 18 loads before any consume (288 B/lane in flight) ----
    LOADG(0, t0);
    LOADG(1, t1);
    LOADG(2, t2);

    ACCG(a00, a01, a02, c00, c01, c02);
    ACCG(a10, a11, a12, c10, c11, c12);
    if (g2) {
        ACCG(a20, a21, a22, c20, c21, c22);
    }
#undef LOADG
#undef NTL
#undef ACCG
#undef ACC

    // 64-lane butterfly reduce all 21 accumulators.
#define RED1(X) X += __shfl_xor(X, off, 64)
    #pragma unroll
    for (int off = 32; off >= 1; off >>= 1) {
        RED1(se0); RED1(se1); RED1(se2);
        RED1(q0);  RED1(q1);  RED1(q2);
        RED1(sr0); RED1(sr1); RED1(sr2);
        RED1(w0);  RED1(w1);  RED1(w2);
        RED1(d00); RED1(d01); RED1(d02);
        RED1(d10); RED1(d11); RED1(d12);
        RED1(d20); RED1(d21); RED1(d22);
    }
#undef RED1

    __shared__ float red[8][NACC];
    const int lane = tid & 63;
    const int wave = tid >> 6;
    if (lane == 0) {
        red[wave][0]  = se0; red[wave][1]  = se1; red[wave][2]  = se2;
        red[wave][3]  = q0;  red[wave][4]  = q1;  red[wave][5]  = q2;
        red[wave][6]  = sr0; red[wave][7]  = sr1; red[wave][8]  = sr2;
        red[wave][9]  = w0;  red[wave][10] = w1;  red[wave][11] = w2;
        red[wave][12] = d00; red[wave][13] = d01; red[wave][14] = d02;
        red[wave][15] = d10; red[wave][16] = d11; red[wave][17] = d12;
        red[wave][18] = d20; red[wave][19] = d21; red[wave][20] = d22;
    }
    __syncthreads();
    // layout: part[chunk*NPAIR + b*NACC + acc] -> coalesced column-sum in finish
    if (tid < NACC) {
        const float s = ((red[0][tid] + red[1][tid]) + (red[2][tid] + red[3][tid]))
                      + ((red[4][tid] + red[5][tid]) + (red[6][tid] + red[7][tid]));
        part[(size_t)chunk * NPAIR + b * NACC + tid] = s;
    }
}

// One block: reduce 16 chunks per (b,acc) column (coalesced), then per-batch
// pair matrix + permutation max, then -mean over batches.
__global__ __launch_bounds__(704) void pit_finish(const float* __restrict__ part,
                                                  float* __restrict__ out) {
    __shared__ float S[NPAIR];
    __shared__ float scores[B_SZ];
    const int p = threadIdx.x;

    if (p < NPAIR) {
        float s = 0.f;
        #pragma unroll
        for (int t = 0; t < NCHUNK; ++t) s += part[(size_t)t * NPAIR + p];
        S[p] = s;
    }
    __syncthreads();

    if (p < B_SZ) {
        const float* v = &S[p * NACC];
        const float invT = 1.0f / (float)T_LEN;
        float se[3] = { v[0], v[1], v[2] };
        float q [3] = { v[3], v[4], v[5] };
        float sr[3] = { v[6], v[7], v[8] };
        float w [3] = { v[9], v[10], v[11] };

        float est_e[3], ref_e[3];
        #pragma unroll
        for (int i = 0; i < 3; ++i) est_e[i] = q[i] - se[i] * se[i] * invT;
        #pragma unroll
        for (int j = 0; j < 3; ++j) ref_e[j] = w[j] - sr[j] * sr[j] * invT;

        float pair[3][3];
        #pragma unroll
        for (int i = 0; i < 3; ++i) {
            #pragma unroll
            for (int j = 0; j < 3; ++j) {
                const float dc = v[12 + i * 3 + j] - se[i] * sr[j] * invT;
                const float te = dc * dc / (ref_e[j] + EPSF);
                const float ne = est_e[i] - te;
                pair[i][j] = 10.0f * log10f(te / (ne + EPSF) + EPSF);
            }
        }
        const float s0 = pair[0][0] + pair[1][1] + pair[2][2];
        const float s1 = pair[0][0] + pair[1][2] + pair[2][1];
        const float s2 = pair[0][1] + pair[1][0] + pair[2][2];
        const float s3 = pair[0][1] + pair[1][2] + pair[2][0];
        const float s4 = pair[0][2] + pair[1][0] + pair[2][1];
        const float s5 = pair[0][2] + pair[1][1] + pair[2][0];
        const float m = fmaxf(fmaxf(fmaxf(s0, s1), fmaxf(s2, s3)), fmaxf(s4, s5));
        scores[p] = m * (1.0f / 3.0f);
    }
    __syncthreads();

    if (p == 0) {
        float s = 0.f;
        #pragma unroll
        for (int b = 0; b < B_SZ; ++b) s += scores[b];
        out[0] = -s * (1.0f / (float)B_SZ);
    }
}

extern "C" void kernel_launch(void* const* d_in, const int* in_sizes, int n_in,
                              void* d_out, int out_size, void* d_ws, size_t ws_size,
                              hipStream_t stream) {
    const float* est = (const float*)d_in[0];
    const float* ref = (const float*)d_in[1];
    float* part = (float*)d_ws;          // NCHUNK * NPAIR floats = 43 KB
    float* out  = (float*)d_out;

    pit_partial<<<dim3(NBLK), dim3(512), 0, stream>>>(est, ref, part);
    pit_finish <<<dim3(1),    dim3(704), 0, stream>>>(part, out);
}

// Round 16
// 20.917 us; speedup vs baseline: 1.0187x; 1.0187x over previous
//
#include <hip/hip_runtime.h>
#include <math.h>

// PIT SI-SDR loss, B=32, C=3, T=96000, fp32 in, scalar fp32 out.
// R15 = R14 (nt loads) with 2 blocks/CU (tail-overlap A/B under nt):
//  (1) pit_partial: 512 blocks (2/CU) x 512 threads, 1500 float4 per block,
//      ALL 18 nt loads issued up front (whole chunk in flight, ~105 VGPR
//      under the (512,2) cap of 128).
//  (2) pit_finish: one block, 16-chunk column sums + 3x3 pair matrix +
//      6-perm max + -mean.
// All reductions fixed-tree -> deterministic.

#define T_LEN  96000
#define T4     24000           // T in float4
#define B_SZ   32
#define NACC   21              // 3 se + 3 se2 + 3 sr + 3 sr2 + 9 dot
#define NPAIR  (B_SZ * NACC)   // 672
#define NCHUNK 16              // chunks per batch; 16*1500 = 24000 exactly
#define CHUNK4 1500            // float4 per chunk (no ragged remainder)
#define NBLK   (B_SZ * NCHUNK) // 512 blocks = 2 blocks/CU on 256 CUs
#define EPSF   1e-8f

typedef float f32x4 __attribute__((ext_vector_type(4)));

__global__ __launch_bounds__(512, 2) void pit_partial(const float* __restrict__ est,
                                                      const float* __restrict__ ref,
                                                      float* __restrict__ part) {
    const int b     = blockIdx.x >> 4;   // / NCHUNK
    const int chunk = blockIdx.x & 15;   // % NCHUNK

    const f32x4* e4 = reinterpret_cast<const f32x4*>(est) + (size_t)b * 3 * T4;
    const f32x4* r4 = reinterpret_cast<const f32x4*>(ref) + (size_t)b * 3 * T4;

    float se0=0.f, se1=0.f, se2=0.f;          // sum est
    float q0 =0.f, q1 =0.f, q2 =0.f;          // sum est^2
    float sr0=0.f, sr1=0.f, sr2=0.f;          // sum ref
    float w0 =0.f, w1 =0.f, w2 =0.f;          // sum ref^2
    float d00=0.f,d01=0.f,d02=0.f;            // dots est_i . ref_j
    float d10=0.f,d11=0.f,d12=0.f;
    float d20=0.f,d21=0.f,d22=0.f;

#define ACC(E0,E1,E2,R0,R1,R2) do {                                   \
        se0 += (E0); se1 += (E1); se2 += (E2);                        \
        q0  += (E0)*(E0); q1 += (E1)*(E1); q2 += (E2)*(E2);           \
        sr0 += (R0); sr1 += (R1); sr2 += (R2);                        \
        w0  += (R0)*(R0); w1 += (R1)*(R1); w2 += (R2)*(R2);           \
        d00 += (E0)*(R0); d01 += (E0)*(R1); d02 += (E0)*(R2);         \
        d10 += (E1)*(R0); d11 += (E1)*(R1); d12 += (E1)*(R2);         \
        d20 += (E2)*(R0); d21 += (E2)*(R1); d22 += (E2)*(R2);         \
    } while (0)

#define ACCG(A0,A1,A2,C0,C1,C2) do {                                  \
        ACC((A0).x, (A1).x, (A2).x, (C0).x, (C1).x, (C2).x);          \
        ACC((A0).y, (A1).y, (A2).y, (C0).y, (C1).y, (C2).y);          \
        ACC((A0).z, (A1).z, (A2).z, (C0).z, (C1).z, (C2).z);          \
        ACC((A0).w, (A1).w, (A2).w, (C0).w, (C1).w, (C2).w);          \
    } while (0)

#define NTL(P) __builtin_nontemporal_load(P)

#define LOADG(G, T) \
        const f32x4 a##G##0 = NTL(&e4[(T)]);            \
        const f32x4 a##G##1 = NTL(&e4[T4 + (T)]);       \
        const f32x4 a##G##2 = NTL(&e4[2 * T4 + (T)]);   \
        const f32x4 c##G##0 = NTL(&r4[(T)]);            \
        const f32x4 c##G##1 = NTL(&r4[T4 + (T)]);       \
        const f32x4 c##G##2 = NTL(&r4[2 * T4 + (T)])

    // 1500 float4 per chunk: 2 full groups of 512 + tail group of 476.
    const int tid = (int)threadIdx.x;
    const int t0  = chunk * CHUNK4 + tid;
    const int t1  = t0 + 512;
    const bool g2 = (tid < (CHUNK4 - 1024));   // tid < 476
    const int t2  = g2 ? (t0 + 1024) : t0;     // always in-bounds

    // ---- issue ALL 18 loads before any consume (288 B/lane in flight) ----
    LOADG(0, t0);
    LOADG(1, t1);
    LOADG(2, t2);

    ACCG(a00, a01, a02, c00, c01, c02);
    ACCG(a10, a11, a12, c10, c11, c12);
    if (g2) {
        ACCG(a20, a21, a22, c20, c21, c22);
    }
#undef LOADG
#undef NTL
#undef ACCG
#undef ACC

    // 64-lane butterfly reduce all 21 accumulators.
#define RED1(X) X += __shfl_xor(X, off, 64)
    #pragma unroll
    for (int off = 32; off >= 1; off >>= 1) {
        RED1(se0); RED1(se1); RED1(se2);
        RED1(q0);  RED1(q1);  RED1(q2);
        RED1(sr0); RED1(sr1); RED1(sr2);
        RED1(w0);  RED1(w1);  RED1(w2);
        RED1(d00); RED1(d01); RED1(d02);
        RED1(d10); RED1(d11); RED1(d12);
        RED1(d20); RED1(d21); RED1(d22);
    }
#undef RED1

    __shared__ float red[8][NACC];
    const int lane = tid & 63;
    const int wave = tid >> 6;
    if (lane == 0) {
        red[wave][0]  = se0; red[wave][1]  = se1; red[wave][2]  = se2;
        red[wave][3]  = q0;  red[wave][4]  = q1;  red[wave][5]  = q2;
        red[wave][6]  = sr0; red[wave][7]  = sr1; red[wave][8]  = sr2;
        red[wave][9]  = w0;  red[wave][10] = w1;  red[wave][11] = w2;
        red[wave][12] = d00; red[wave][13] = d01; red[wave][14] = d02;
        red[wave][15] = d10; red[wave][16] = d11; red[wave][17] = d12;
        red[wave][18] = d20; red[wave][19] = d21; red[wave][20] = d22;
    }
    __syncthreads();
    // layout: part[chunk*NPAIR + b*NACC + acc] -> coalesced column-sum in finish
    if (tid < NACC) {
        const float s = ((red[0][tid] + red[1][tid]) + (red[2][tid] + red[3][tid]))
                      + ((red[4][tid] + red[5][tid]) + (red[6][tid] + red[7][tid]));
        part[(size_t)chunk * NPAIR + b * NACC + tid] = s;
    }
}

// One block: reduce 16 chunks per (b,acc) column (coalesced), then per-batch
// pair matrix + permutation max, then -mean over batches.
__global__ __launch_bounds__(704) void pit_finish(const float* __restrict__ part,
                                                  float* __restrict__ out) {
    __shared__ float S[NPAIR];
    __shared__ float scores[B_SZ];
    const int p = threadIdx.x;

    if (p < NPAIR) {
        float s = 0.f;
        #pragma unroll
        for (int t = 0; t < NCHUNK; ++t) s += part[(size_t)t * NPAIR + p];
        S[p] = s;
    }
    __syncthreads();

    if (p < B_SZ) {
        const float* v = &S[p * NACC];
        const float invT = 1.0f / (float)T_LEN;
        float se[3] = { v[0], v[1], v[2] };
        float q [3] = { v[3], v[4], v[5] };
        float sr[3] = { v[6], v[7], v[8] };
        float w [3] = { v[9], v[10], v[11] };

        float est_e[3], ref_e[3];
        #pragma unroll
        for (int i = 0; i < 3; ++i) est_e[i] = q[i] - se[i] * se[i] * invT;
        #pragma unroll
        for (int j = 0; j < 3; ++j) ref_e[j] = w[j] - sr[j] * sr[j] * invT;

        float pair[3][3];
        #pragma unroll
        for (int i = 0; i < 3; ++i) {
            #pragma unroll
            for (int j = 0; j < 3; ++j) {
                const float dc = v[12 + i * 3 + j] - se[i] * sr[j] * invT;
                const float te = dc * dc / (ref_e[j] + EPSF);
                const float ne = est_e[i] - te;
                pair[i][j] = 10.0f * log10f(te / (ne + EPSF) + EPSF);
            }
        }
        const float s0 = pair[0][0] + pair[1][1] + pair[2][2];
        const float s1 = pair[0][0] + pair[1][2] + pair[2][1];
        const float s2 = pair[0][1] + pair[1][0] + pair[2][2];
        const float s3 = pair[0][1] + pair[1][2] + pair[2][0];
        const float s4 = pair[0][2] + pair[1][0] + pair[2][1];
        const float s5 = pair[0][2] + pair[1][1] + pair[2][0];
        const float m = fmaxf(fmaxf(fmaxf(s0, s1), fmaxf(s2, s3)), fmaxf(s4, s5));
        scores[p] = m * (1.0f / 3.0f);
    }
    __syncthreads();

    if (p == 0) {
        float s = 0.f;
        #pragma unroll
        for (int b = 0; b < B_SZ; ++b) s += scores[b];
        out[0] = -s * (1.0f / (float)B_SZ);
    }
}

extern "C" void kernel_launch(void* const* d_in, const int* in_sizes, int n_in,
                              void* d_out, int out_size, void* d_ws, size_t ws_size,
                              hipStream_t stream) {
    const float* est = (const float*)d_in[0];
    const float* ref = (const float*)d_in[1];
    float* part = (float*)d_ws;          // NCHUNK * NPAIR floats = 43 KB
    float* out  = (float*)d_out;

    pit_partial<<<dim3(NBLK), dim3(512), 0, stream>>>(est, ref, part);
    pit_finish <<<dim3(1),    dim3(704), 0, stream>>>(part, out);
}

// Round 17
// 20.485 us; speedup vs baseline: 1.0402x; 1.0211x over previous
//
#include <hip/hip_runtime.h>
#include <math.h>

// PIT SI-SDR loss, B=32, C=3, T=96000, fp32 in, scalar fp32 out.
// R17 = R14 with 1024 threads/block (4 waves/SIMD instead of 2; wave-TLP A/B):
//  (1) pit_partial: 256 blocks (1/CU) x 1024 threads, 3000 float4 per block,
//      depth-3 rolling nt-load pipeline (18 loads/lane in flight, ~105 VGPR
//      under the (1024,1) cap of 128).
//  (2) pit_finish: one block, 8-chunk column sums + 3x3 pair matrix +
//      6-perm max + -mean.
// All reductions fixed-tree -> deterministic.

#define T_LEN  96000
#define T4     24000           // T in float4
#define B_SZ   32
#define NACC   21              // 3 se + 3 se2 + 3 sr + 3 sr2 + 9 dot
#define NPAIR  (B_SZ * NACC)   // 672
#define NCHUNK 8               // chunks per batch; 8*3000 = 24000 exactly
#define CHUNK4 3000            // float4 per chunk (no ragged remainder)
#define NBLK   (B_SZ * NCHUNK) // 256 blocks = 1 block/CU on 256 CUs
#define EPSF   1e-8f

typedef float f32x4 __attribute__((ext_vector_type(4)));

__global__ __launch_bounds__(1024, 1) void pit_partial(const float* __restrict__ est,
                                                       const float* __restrict__ ref,
                                                       float* __restrict__ part) {
    const int b     = blockIdx.x >> 3;   // / NCHUNK
    const int chunk = blockIdx.x & 7;    // % NCHUNK

    const f32x4* e4 = reinterpret_cast<const f32x4*>(est) + (size_t)b * 3 * T4;
    const f32x4* r4 = reinterpret_cast<const f32x4*>(ref) + (size_t)b * 3 * T4;

    float se0=0.f, se1=0.f, se2=0.f;          // sum est
    float q0 =0.f, q1 =0.f, q2 =0.f;          // sum est^2
    float sr0=0.f, sr1=0.f, sr2=0.f;          // sum ref
    float w0 =0.f, w1 =0.f, w2 =0.f;          // sum ref^2
    float d00=0.f,d01=0.f,d02=0.f;            // dots est_i . ref_j
    float d10=0.f,d11=0.f,d12=0.f;
    float d20=0.f,d21=0.f,d22=0.f;

#define ACC(E0,E1,E2,R0,R1,R2) do {                                   \
        se0 += (E0); se1 += (E1); se2 += (E2);                        \
        q0  += (E0)*(E0); q1 += (E1)*(E1); q2 += (E2)*(E2);           \
        sr0 += (R0); sr1 += (R1); sr2 += (R2);                        \
        w0  += (R0)*(R0); w1 += (R1)*(R1); w2 += (R2)*(R2);           \
        d00 += (E0)*(R0); d01 += (E0)*(R1); d02 += (E0)*(R2);         \
        d10 += (E1)*(R0); d11 += (E1)*(R1); d12 += (E1)*(R2);         \
        d20 += (E2)*(R0); d21 += (E2)*(R1); d22 += (E2)*(R2);         \
    } while (0)

#define ACCG(A0,A1,A2,C0,C1,C2) do {                                  \
        ACC((A0).x, (A1).x, (A2).x, (C0).x, (C1).x, (C2).x);          \
        ACC((A0).y, (A1).y, (A2).y, (C0).y, (C1).y, (C2).y);          \
        ACC((A0).z, (A1).z, (A2).z, (C0).z, (C1).z, (C2).z);          \
        ACC((A0).w, (A1).w, (A2).w, (C0).w, (C1).w, (C2).w);          \
    } while (0)

#define NTL(P) __builtin_nontemporal_load(P)

#define LOADG(G, T) \
        const f32x4 a##G##0 = NTL(&e4[(T)]);            \
        const f32x4 a##G##1 = NTL(&e4[T4 + (T)]);       \
        const f32x4 a##G##2 = NTL(&e4[2 * T4 + (T)]);   \
        const f32x4 c##G##0 = NTL(&r4[(T)]);            \
        const f32x4 c##G##1 = NTL(&r4[T4 + (T)]);       \
        const f32x4 c##G##2 = NTL(&r4[2 * T4 + (T)])

    // 3000 float4 per chunk: 2 full groups of 1024 + tail group of 952.
    const int tid = (int)threadIdx.x;
    const int t0  = chunk * CHUNK4 + tid;
    const int t1  = t0 + 1024;
    const bool g2 = (tid < (CHUNK4 - 2048));   // tid < 952
    const int t2  = g2 ? (t0 + 2048) : t0;     // always in-bounds

    // ---- issue ALL 18 loads before any consume (288 B/lane in flight) ----
    LOADG(0, t0);
    LOADG(1, t1);
    LOADG(2, t2);

    ACCG(a00, a01, a02, c00, c01, c02);
    ACCG(a10, a11, a12, c10, c11, c12);
    if (g2) {
        ACCG(a20, a21, a22, c20, c21, c22);
    }
#undef LOADG
#undef NTL
#undef ACCG
#undef ACC

    // 64-lane butterfly reduce all 21 accumulators.
#define RED1(X) X += __shfl_xor(X, off, 64)
    #pragma unroll
    for (int off = 32; off >= 1; off >>= 1) {
        RED1(se0); RED1(se1); RED1(se2);
        RED1(q0);  RED1(q1);  RED1(q2);
        RED1(sr0); RED1(sr1); RED1(sr2);
        RED1(w0);  RED1(w1);  RED1(w2);
        RED1(d00); RED1(d01); RED1(d02);
        RED1(d10); RED1(d11); RED1(d12);
        RED1(d20); RED1(d21); RED1(d22);
    }
#undef RED1

    __shared__ float red[16][NACC];
    const int lane = tid & 63;
    const int wave = tid >> 6;
    if (lane == 0) {
        red[wave][0]  = se0; red[wave][1]  = se1; red[wave][2]  = se2;
        red[wave][3]  = q0;  red[wave][4]  = q1;  red[wave][5]  = q2;
        red[wave][6]  = sr0; red[wave][7]  = sr1; red[wave][8]  = sr2;
        red[wave][9]  = w0;  red[wave][10] = w1;  red[wave][11] = w2;
        red[wave][12] = d00; red[wave][13] = d01; red[wave][14] = d02;
        red[wave][15] = d10; red[wave][16] = d11; red[wave][17] = d12;
        red[wave][18] = d20; red[wave][19] = d21; red[wave][20] = d22;
    }
    __syncthreads();
    // layout: part[chunk*NPAIR + b*NACC + acc] -> coalesced column-sum in finish
    if (tid < NACC) {
        float s = 0.f;
        #pragma unroll
        for (int wv = 0; wv < 16; ++wv) s += red[wv][tid];
        part[(size_t)chunk * NPAIR + b * NACC + tid] = s;
    }
}

// One block: reduce 8 chunks per (b,acc) column (coalesced), then per-batch
// pair matrix + permutation max, then -mean over batches.
__global__ __launch_bounds__(704) void pit_finish(const float* __restrict__ part,
                                                  float* __restrict__ out) {
    __shared__ float S[NPAIR];
    __shared__ float scores[B_SZ];
    const int p = threadIdx.x;

    if (p < NPAIR) {
        float s = 0.f;
        #pragma unroll
        for (int t = 0; t < NCHUNK; ++t) s += part[(size_t)t * NPAIR + p];
        S[p] = s;
    }
    __syncthreads();

    if (p < B_SZ) {
        const float* v = &S[p * NACC];
        const float invT = 1.0f / (float)T_LEN;
        float se[3] = { v[0], v[1], v[2] };
        float q [3] = { v[3], v[4], v[5] };
        float sr[3] = { v[6], v[7], v[8] };
        float w [3] = { v[9], v[10], v[11] };

        float est_e[3], ref_e[3];
        #pragma unroll
        for (int i = 0; i < 3; ++i) est_e[i] = q[i] - se[i] * se[i] * invT;
        #pragma unroll
        for (int j = 0; j < 3; ++j) ref_e[j] = w[j] - sr[j] * sr[j] * invT;

        float pair[3][3];
        #pragma unroll
        for (int i = 0; i < 3; ++i) {
            #pragma unroll
            for (int j = 0; j < 3; ++j) {
                const float dc = v[12 + i * 3 + j] - se[i] * sr[j] * invT;
                const float te = dc * dc / (ref_e[j] + EPSF);
                const float ne = est_e[i] - te;
                pair[i][j] = 10.0f * log10f(te / (ne + EPSF) + EPSF);
            }
        }
        const float s0 = pair[0][0] + pair[1][1] + pair[2][2];
        const float s1 = pair[0][0] + pair[1][2] + pair[2][1];
        const float s2 = pair[0][1] + pair[1][0] + pair[2][2];
        const float s3 = pair[0][1] + pair[1][2] + pair[2][0];
        const float s4 = pair[0][2] + pair[1][0] + pair[2][1];
        const float s5 = pair[0][2] + pair[1][1] + pair[2][0];
        const float m = fmaxf(fmaxf(fmaxf(s0, s1), fmaxf(s2, s3)), fmaxf(s4, s5));
        scores[p] = m * (1.0f / 3.0f);
    }
    __syncthreads();

    if (p == 0) {
        float s = 0.f;
        #pragma unroll
        for (int b = 0; b < B_SZ; ++b) s += scores[b];
        out[0] = -s * (1.0f / (float)B_SZ);
    }
}

extern "C" void kernel_launch(void* const* d_in, const int* in_sizes, int n_in,
                              void* d_out, int out_size, void* d_ws, size_t ws_size,
                              hipStream_t stream) {
    const float* est = (const float*)d_in[0];
    const float* ref = (const float*)d_in[1];
    float* part = (float*)d_ws;          // NCHUNK * NPAIR floats = 21.5 KB
    float* out  = (float*)d_out;

    pit_partial<<<dim3(NBLK), dim3(1024), 0, stream>>>(est, ref, part);
    pit_finish <<<dim3(1),    dim3(704),  0, stream>>>(part, out);
}

// Round 18
// 19.243 us; speedup vs baseline: 1.1073x; 1.0645x over previous
//
#include <hip/hip_runtime.h>
#include <math.h>

// PIT SI-SDR loss, B=32, C=3, T=96000, fp32 in, scalar fp32 out.
// FINAL (champion R14 restored): two kernels.
//  (1) pit_partial: 256 blocks (exactly 1/CU) x 512 threads, 3000 float4 per
//      block, depth-3 rolling NONTEMPORAL load pipeline (18 loads in flight).
//      Config chosen by exhaustive A/B scans: blocks/CU {1,2,4,6} -> 1;
//      threads {256,512,1024} -> 512; MLP {12,18,36} -> 18; nt loads -2.2us.
//      In-kernel fusion (grid.sync / fences / atomics) measured >=10us worse.
//  (2) pit_finish: one block, 8-chunk column sums + 3x3 pair matrix +
//      6-perm max + -mean.
// All reductions fixed-tree -> deterministic. absmax 0.0 vs reference.

#define T_LEN  96000
#define T4     24000           // T in float4
#define B_SZ   32
#define NACC   21              // 3 se + 3 se2 + 3 sr + 3 sr2 + 9 dot
#define NPAIR  (B_SZ * NACC)   // 672
#define NCHUNK 8               // chunks per batch; 8*3000 = 24000 exactly
#define CHUNK4 3000            // float4 per chunk (no ragged remainder)
#define NBLK   (B_SZ * NCHUNK) // 256 blocks = 1 block/CU on 256 CUs
#define EPSF   1e-8f

typedef float f32x4 __attribute__((ext_vector_type(4)));

__global__ __launch_bounds__(512, 1) void pit_partial(const float* __restrict__ est,
                                                      const float* __restrict__ ref,
                                                      float* __restrict__ part) {
    const int b     = blockIdx.x >> 3;   // / NCHUNK
    const int chunk = blockIdx.x & 7;    // % NCHUNK

    const f32x4* e4 = reinterpret_cast<const f32x4*>(est) + (size_t)b * 3 * T4;
    const f32x4* r4 = reinterpret_cast<const f32x4*>(ref) + (size_t)b * 3 * T4;

    float se0=0.f, se1=0.f, se2=0.f;          // sum est
    float q0 =0.f, q1 =0.f, q2 =0.f;          // sum est^2
    float sr0=0.f, sr1=0.f, sr2=0.f;          // sum ref
    float w0 =0.f, w1 =0.f, w2 =0.f;          // sum ref^2
    float d00=0.f,d01=0.f,d02=0.f;            // dots est_i . ref_j
    float d10=0.f,d11=0.f,d12=0.f;
    float d20=0.f,d21=0.f,d22=0.f;

#define ACC(E0,E1,E2,R0,R1,R2) do {                                   \
        se0 += (E0); se1 += (E1); se2 += (E2);                        \
        q0  += (E0)*(E0); q1 += (E1)*(E1); q2 += (E2)*(E2);           \
        sr0 += (R0); sr1 += (R1); sr2 += (R2);                        \
        w0  += (R0)*(R0); w1 += (R1)*(R1); w2 += (R2)*(R2);           \
        d00 += (E0)*(R0); d01 += (E0)*(R1); d02 += (E0)*(R2);         \
        d10 += (E1)*(R0); d11 += (E1)*(R1); d12 += (E1)*(R2);         \
        d20 += (E2)*(R0); d21 += (E2)*(R1); d22 += (E2)*(R2);         \
    } while (0)

#define ACCG(A0,A1,A2,C0,C1,C2) do {                                  \
        ACC((A0).x, (A1).x, (A2).x, (C0).x, (C1).x, (C2).x);          \
        ACC((A0).y, (A1).y, (A2).y, (C0).y, (C1).y, (C2).y);          \
        ACC((A0).z, (A1).z, (A2).z, (C0).z, (C1).z, (C2).z);          \
        ACC((A0).w, (A1).w, (A2).w, (C0).w, (C1).w, (C2).w);          \
    } while (0)

#define NTL(P) __builtin_nontemporal_load(P)

#define LOADG(G, T) \
        const f32x4 a##G##0 = NTL(&e4[(T)]);            \
        const f32x4 a##G##1 = NTL(&e4[T4 + (T)]);       \
        const f32x4 a##G##2 = NTL(&e4[2 * T4 + (T)]);   \
        const f32x4 c##G##0 = NTL(&r4[(T)]);            \
        const f32x4 c##G##1 = NTL(&r4[T4 + (T)]);       \
        const f32x4 c##G##2 = NTL(&r4[2 * T4 + (T)])

    // 3000 float4 per chunk: 5 full groups of 512 + tail group of 440.
    const int tid = (int)threadIdx.x;
    const int t0  = chunk * CHUNK4 + tid;
    const int t1  = t0 + 512;
    const int t2  = t0 + 1024;
    const int t3  = t0 + 1536;
    const int t4v = t0 + 2048;
    const bool g5 = (tid < (CHUNK4 - 2560));   // tid < 440
    const int t5  = g5 ? (t0 + 2560) : t0;     // always in-bounds

    // depth-3 rolling pipeline: 18 loads in flight throughout.
    LOADG(0, t0);
    LOADG(1, t1);
    LOADG(2, t2);
    ACCG(a00, a01, a02, c00, c01, c02);
    LOADG(3, t3);
    ACCG(a10, a11, a12, c10, c11, c12);
    LOADG(4, t4v);
    ACCG(a20, a21, a22, c20, c21, c22);
    LOADG(5, t5);
    ACCG(a30, a31, a32, c30, c31, c32);
    ACCG(a40, a41, a42, c40, c41, c42);
    if (g5) {
        ACCG(a50, a51, a52, c50, c51, c52);
    }
#undef LOADG
#undef NTL
#undef ACCG
#undef ACC

    // 64-lane butterfly reduce all 21 accumulators.
#define RED1(X) X += __shfl_xor(X, off, 64)
    #pragma unroll
    for (int off = 32; off >= 1; off >>= 1) {
        RED1(se0); RED1(se1); RED1(se2);
        RED1(q0);  RED1(q1);  RED1(q2);
        RED1(sr0); RED1(sr1); RED1(sr2);
        RED1(w0);  RED1(w1);  RED1(w2);
        RED1(d00); RED1(d01); RED1(d02);
        RED1(d10); RED1(d11); RED1(d12);
        RED1(d20); RED1(d21); RED1(d22);
    }
#undef RED1

    __shared__ float red[8][NACC];
    const int lane = tid & 63;
    const int wave = tid >> 6;
    if (lane == 0) {
        red[wave][0]  = se0; red[wave][1]  = se1; red[wave][2]  = se2;
        red[wave][3]  = q0;  red[wave][4]  = q1;  red[wave][5]  = q2;
        red[wave][6]  = sr0; red[wave][7]  = sr1; red[wave][8]  = sr2;
        red[wave][9]  = w0;  red[wave][10] = w1;  red[wave][11] = w2;
        red[wave][12] = d00; red[wave][13] = d01; red[wave][14] = d02;
        red[wave][15] = d10; red[wave][16] = d11; red[wave][17] = d12;
        red[wave][18] = d20; red[wave][19] = d21; red[wave][20] = d22;
    }
    __syncthreads();
    // layout: part[chunk*NPAIR + b*NACC + acc] -> coalesced column-sum in finish
    if (tid < NACC) {
        const float s = ((red[0][tid] + red[1][tid]) + (red[2][tid] + red[3][tid]))
                      + ((red[4][tid] + red[5][tid]) + (red[6][tid] + red[7][tid]));
        part[(size_t)chunk * NPAIR + b * NACC + tid] = s;
    }
}

// One block: reduce 8 chunks per (b,acc) column (coalesced), then per-batch
// pair matrix + permutation max, then -mean over batches.
__global__ __launch_bounds__(704) void pit_finish(const float* __restrict__ part,
                                                  float* __restrict__ out) {
    __shared__ float S[NPAIR];
    __shared__ float scores[B_SZ];
    const int p = threadIdx.x;

    if (p < NPAIR) {
        float s = 0.f;
        #pragma unroll
        for (int t = 0; t < NCHUNK; ++t) s += part[(size_t)t * NPAIR + p];
        S[p] = s;
    }
    __syncthreads();

    if (p < B_SZ) {
        const float* v = &S[p * NACC];
        const float invT = 1.0f / (float)T_LEN;
        float se[3] = { v[0], v[1], v[2] };
        float q [3] = { v[3], v[4], v[5] };
        float sr[3] = { v[6], v[7], v[8] };
        float w [3] = { v[9], v[10], v[11] };

        float est_e[3], ref_e[3];
        #pragma unroll
        for (int i = 0; i < 3; ++i) est_e[i] = q[i] - se[i] * se[i] * invT;
        #pragma unroll
        for (int j = 0; j < 3; ++j) ref_e[j] = w[j] - sr[j] * sr[j] * invT;

        float pair[3][3];
        #pragma unroll
        for (int i = 0; i < 3; ++i) {
            #pragma unroll
            for (int j = 0; j < 3; ++j) {
                const float dc = v[12 + i * 3 + j] - se[i] * sr[j] * invT;
                const float te = dc * dc / (ref_e[j] + EPSF);
                const float ne = est_e[i] - te;
                pair[i][j] = 10.0f * log10f(te / (ne + EPSF) + EPSF);
            }
        }
        const float s0 = pair[0][0] + pair[1][1] + pair[2][2];
        const float s1 = pair[0][0] + pair[1][2] + pair[2][1];
        const float s2 = pair[0][1] + pair[1][0] + pair[2][2];
        const float s3 = pair[0][1] + pair[1][2] + pair[2][0];
        const float s4 = pair[0][2] + pair[1][0] + pair[2][1];
        const float s5 = pair[0][2] + pair[1][1] + pair[2][0];
        const float m = fmaxf(fmaxf(fmaxf(s0, s1), fmaxf(s2, s3)), fmaxf(s4, s5));
        scores[p] = m * (1.0f / 3.0f);
    }
    __syncthreads();

    if (p == 0) {
        float s = 0.f;
        #pragma unroll
        for (int b = 0; b < B_SZ; ++b) s += scores[b];
        out[0] = -s * (1.0f / (float)B_SZ);
    }
}

extern "C" void kernel_launch(void* const* d_in, const int* in_sizes, int n_in,
                              void* d_out, int out_size, void* d_ws, size_t ws_size,
                              hipStream_t stream) {
    const float* est = (const float*)d_in[0];
    const float* ref = (const float*)d_in[1];
    float* part = (float*)d_ws;          // NCHUNK * NPAIR floats = 21.5 KB
    float* out  = (float*)d_out;

    pit_partial<<<dim3(NBLK), dim3(512), 0, stream>>>(est, ref, part);
    pit_finish <<<dim3(1),    dim3(704), 0, stream>>>(part, out);
}